// Round 1
// baseline (2134.089 us; speedup 1.0000x reference)
//
#include <hip/hip_runtime.h>
#include <cmath>

#define B_ 32
#define T_ 2000
#define D_ 1024
#define U_ 1024
#define M_ (B_*T_)

// ---------------- kernel 1: fused y[m] = sum_u relu(x[m,:]·W[:,u] + db[u]) * wv[u]
// 128x128 tile, BK=16, 256 threads, 8x8 per-thread register tile.
__global__ __launch_bounds__(256) void cif_gemm(const float* __restrict__ x,
                                                const float* __restrict__ W,
                                                const float* __restrict__ db,
                                                const float* __restrict__ wv,
                                                float* __restrict__ y)
{
    __shared__ float smem[16*128 + 16*128];
    float (*As)[128] = (float (*)[128])smem;            // As[k][m] (transposed)
    float (*Bs)[128] = (float (*)[128])(smem + 16*128); // Bs[k][n]
    const int tid = threadIdx.x;
    const int m0  = blockIdx.x * 128;
    const int tm  = tid & 15;   // fast within wave -> A reads 2-way (free)
    const int tn  = tid >> 4;   // slow within wave -> B reads broadcast
    float rp[8] = {0.f,0.f,0.f,0.f,0.f,0.f,0.f,0.f};

    for (int nb = 0; nb < 8; ++nb) {
        const int n0 = nb * 128;
        float acc[8][8];
#pragma unroll
        for (int i = 0; i < 8; ++i)
#pragma unroll
            for (int j = 0; j < 8; ++j) acc[i][j] = 0.f;

        for (int k0 = 0; k0 < 1024; k0 += 16) {
            // stage A: 128 rows x 16 k  (512 float4)
#pragma unroll
            for (int l = 0; l < 2; ++l) {
                const int i   = tid + l*256;
                const int row = i >> 2, c4 = i & 3;
                const float4 va = *(const float4*)(x + (size_t)(m0+row)*1024 + k0 + c4*4);
                As[c4*4+0][row] = va.x; As[c4*4+1][row] = va.y;
                As[c4*4+2][row] = va.z; As[c4*4+3][row] = va.w;
            }
            // stage B: 16 k x 128 n
#pragma unroll
            for (int l = 0; l < 2; ++l) {
                const int i  = tid + l*256;
                const int cr = i >> 5, j4 = i & 31;
                *(float4*)(&Bs[cr][j4*4]) =
                    *(const float4*)(W + (size_t)(k0+cr)*1024 + n0 + j4*4);
            }
            __syncthreads();
#pragma unroll
            for (int kk = 0; kk < 16; ++kk) {
                const float4 a0 = *(const float4*)&As[kk][tm*4];
                const float4 a1 = *(const float4*)&As[kk][64 + tm*4];
                const float4 b0 = *(const float4*)&Bs[kk][tn*4];
                const float4 b1 = *(const float4*)&Bs[kk][64 + tn*4];
                const float a[8]  = {a0.x,a0.y,a0.z,a0.w,a1.x,a1.y,a1.z,a1.w};
                const float bb[8] = {b0.x,b0.y,b0.z,b0.w,b1.x,b1.y,b1.z,b1.w};
#pragma unroll
                for (int i = 0; i < 8; ++i)
#pragma unroll
                    for (int j = 0; j < 8; ++j)
                        acc[i][j] = fmaf(a[i], bb[j], acc[i][j]);
            }
            __syncthreads();
        }
        // epilogue for this N-block: bias + relu + dot with wv, accumulate row partials
        const float4 d0 = *(const float4*)(db + n0 + tn*4);
        const float4 d1 = *(const float4*)(db + n0 + 64 + tn*4);
        const float4 v0 = *(const float4*)(wv + n0 + tn*4);
        const float4 v1 = *(const float4*)(wv + n0 + 64 + tn*4);
        const float dd[8] = {d0.x,d0.y,d0.z,d0.w,d1.x,d1.y,d1.z,d1.w};
        const float vv[8] = {v0.x,v0.y,v0.z,v0.w,v1.x,v1.y,v1.z,v1.w};
#pragma unroll
        for (int i = 0; i < 8; ++i) {
            float s = 0.f;
#pragma unroll
            for (int j = 0; j < 8; ++j) {
                float h = acc[i][j] + dd[j];
                h = fmaxf(h, 0.f);
                s = fmaf(h, vv[j], s);
            }
            rp[i] += s;
        }
    }
    // deterministic cross-thread (tn) reduce of row partials via LDS
    __syncthreads();
    float* red = smem;  // 16 x 128 floats
#pragma unroll
    for (int i = 0; i < 8; ++i) {
        const int row = (i < 4) ? (tm*4 + i) : (64 + tm*4 + (i-4));
        red[tn*128 + row] = rp[i];
    }
    __syncthreads();
    if (tid < 128) {
        float s = 0.f;
#pragma unroll
        for (int t = 0; t < 16; ++t) s += red[t*128 + tid];
        y[m0 + tid] = s;
    }
}

// ---------------- kernel 2: sigmoid, mask, per-batch sum (fp64), quantity, normalize
__global__ __launch_bounds__(256) void cif_wnorm(const float* __restrict__ y,
                                                 const unsigned char* __restrict__ mask,
                                                 const int* __restrict__ tlen,
                                                 const float* __restrict__ wb,
                                                 float* __restrict__ wn,
                                                 float* __restrict__ qty,
                                                 int* __restrict__ padc)
{
    const int b = blockIdx.x, tid = threadIdx.x;
    const double wbias = (double)wb[0];
    double lsum = 0.0; int lpad = 0;
    for (int t = tid; t < T_; t += 256) {
        const double z = (double)y[b*T_ + t] + wbias;
        double s = 1.0 / (1.0 + exp(-z));
        const unsigned char mk = mask[b*T_ + t];
        if (mk) s = 0.0; else ++lpad;
        wn[b*T_ + t] = (float)s;
        lsum += s;
    }
    __shared__ double sred[256];
    __shared__ int    ired[256];
    sred[tid] = lsum; ired[tid] = lpad;
    __syncthreads();
    for (int st = 128; st > 0; st >>= 1) {
        if (tid < st) { sred[tid] += sred[tid+st]; ired[tid] += ired[tid+st]; }
        __syncthreads();
    }
    __shared__ double sc;
    if (tid == 0) {
        qty[b]  = (float)sred[0];                 // quantity_out (pre-normalization sum)
        sc      = (double)tlen[b] / sred[0];
        padc[b] = ired[0];
    }
    __syncthreads();
    const double scale = sc;
    for (int t = tid; t < T_; t += 256)
        wn[b*T_ + t] = (float)((double)wn[b*T_ + t] * scale);
}

// ---------------- kernel 3: scalar integrate-and-fire scan (one lane per batch)
__global__ void cif_scan(float* __restrict__ wn,
                         const int* __restrict__ padc,
                         int* __restrict__ fire_t,
                         float* __restrict__ carry,
                         int* __restrict__ nf)
{
    const int b = threadIdx.x;
    if (b >= B_) return;
    float acc = 0.f; int k = 0;
    const int pc = padc[b];
    for (int t = 0; t < T_; ++t) {
        const float w = wn[b*T_ + t];
        const float s = acc + w;
        if (s >= 1.0f) {                 // fired
            const float rem = 1.0f - acc;
            const float cw  = w - rem;   // leftover opens next segment
            if (t <= pc && k < 256) {    // ref zeroes f_s when t > pad_start
                fire_t[b*256 + k] = t;
                carry [b*256 + k] = cw;
                wn[b*T_ + t] = rem;      // coefficient at the firing step
                ++k;
            }
            acc = cw;
        } else {
            acc = s;
        }
    }
    nf[b] = k;
}

// ---------------- kernel 4: segmented weighted gather -> cif_out rows
__global__ __launch_bounds__(256) void cif_scatter(const float* __restrict__ x,
                                                   const float* __restrict__ wn,
                                                   const int* __restrict__ fire_t,
                                                   const float* __restrict__ carry,
                                                   const int* __restrict__ nf,
                                                   float* __restrict__ out)
{
    const int k = blockIdx.x, b = blockIdx.y;
    if (k >= nf[b]) return;
    const int tk = fire_t[b*256 + k];
    const int d  = threadIdx.x * 4;
    const float* xb = x + (size_t)b * T_ * 1024;
    float ax = 0.f, ay = 0.f, az = 0.f, aw = 0.f;
    int ts = 0;
    if (k > 0) {
        const int   tp = fire_t[b*256 + k - 1];
        const float c  = carry [b*256 + k - 1];
        const float4 xv = *(const float4*)(xb + (size_t)tp*1024 + d);
        ax = c*xv.x; ay = c*xv.y; az = c*xv.z; aw = c*xv.w;
        ts = tp + 1;
    }
    for (int t = ts; t <= tk; ++t) {
        const float c = wn[b*T_ + t];   // rem at t==tk (set by scan), w otherwise
        const float4 xv = *(const float4*)(xb + (size_t)t*1024 + d);
        ax = fmaf(c, xv.x, ax); ay = fmaf(c, xv.y, ay);
        az = fmaf(c, xv.z, az); aw = fmaf(c, xv.w, aw);
    }
    float4 r; r.x = ax; r.y = ay; r.z = az; r.w = aw;
    *(float4*)(out + ((size_t)b*T_ + k)*1024 + d) = r;
}

// ---------------- kernel 5: cif_out_padding_mask (written as float 0/1)
__global__ void cif_mask(const int* __restrict__ nf, float* __restrict__ mout)
{
    const int i = blockIdx.x * 256 + threadIdx.x;
    if (i >= B_*T_) return;
    const int b = i / T_, t = i - b*T_;
    mout[i] = (t < nf[b]) ? 1.0f : 0.0f;
}

extern "C" void kernel_launch(void* const* d_in, const int* in_sizes, int n_in,
                              void* d_out, int out_size, void* d_ws, size_t ws_size,
                              hipStream_t stream)
{
    const float*         x    = (const float*)d_in[0];
    const unsigned char* mask = (const unsigned char*)d_in[1]; // bool array (all false)
    const int*           tlen = (const int*)d_in[2];
    const float*         dW   = (const float*)d_in[3];
    const float*         db   = (const float*)d_in[4];
    const float*         wv   = (const float*)d_in[5];  // weight_w (U,1)
    const float*         wb   = (const float*)d_in[6];

    float* out  = (float*)d_out;                 // cif_out [B,T,D]
    float* qty  = out + (size_t)B_*T_*D_;        // quantity_out [B]
    float* mout = qty + B_;                      // padding mask [B,T] as float 0/1

    float* ws     = (float*)d_ws;
    float* y      = ws;                          // 64000
    float* wn     = ws + M_;                     // 64000
    float* carry  = ws + 2*M_;                   // 32*256
    int*   fire_t = (int*)(ws + 2*M_ + B_*256);  // 32*256
    int*   nf     = (int*)(ws + 2*M_ + 2*B_*256);      // 32
    int*   padc   = nf + B_;                           // 32

    hipMemsetAsync(d_out, 0, (size_t)out_size * sizeof(float), stream);

    cif_gemm   <<<M_/128, 256, 0, stream>>>(x, dW, db, wv, y);
    cif_wnorm  <<<B_,     256, 0, stream>>>(y, mask, tlen, wb, wn, qty, padc);
    cif_scan   <<<1,       64, 0, stream>>>(wn, padc, fire_t, carry, nf);
    cif_scatter<<<dim3(250, B_), 256, 0, stream>>>(x, wn, fire_t, carry, nf, out);
    cif_mask   <<<(B_*T_ + 255)/256, 256, 0, stream>>>(nf, mout);
}

// Round 3
// 1155.915 us; speedup vs baseline: 1.8462x; 1.8462x over previous
//
#include <hip/hip_runtime.h>
#include <cmath>

#define B_ 32
#define T_ 2000
#define D_ 1024
#define U_ 1024
#define M_ (B_*T_)

typedef float  f32x4  __attribute__((ext_vector_type(4)));
typedef short  bf16x8 __attribute__((ext_vector_type(8)));
typedef unsigned short us4 __attribute__((ext_vector_type(4)));
typedef unsigned short us8 __attribute__((ext_vector_type(8)));

// ---------------- kernel 0: W [k][n] f32 -> W^T hi/lo bf16 [n][k]
__global__ __launch_bounds__(256) void wt_conv(const float* __restrict__ W,
                                               unsigned short* __restrict__ WhT,
                                               unsigned short* __restrict__ WlT)
{
    __shared__ float tl[32][33];
    const int tx = threadIdx.x & 31, ty = threadIdx.x >> 5; // ty 0..7
    const int n0 = blockIdx.x * 32, k0 = blockIdx.y * 32;
#pragma unroll
    for (int i = 0; i < 4; ++i)
        tl[ty + i*8][tx] = W[(size_t)(k0 + ty + i*8)*1024 + n0 + tx];
    __syncthreads();
#pragma unroll
    for (int i = 0; i < 4; ++i) {
        const float f = tl[tx][ty + i*8];
        const unsigned u = __float_as_uint(f);
        const float hif = __uint_as_float(u & 0xFFFF0000u);
        const unsigned lo = __float_as_uint(f - hif);
        WhT[(size_t)(n0 + ty + i*8)*1024 + k0 + tx] = (unsigned short)(u >> 16);
        WlT[(size_t)(n0 + ty + i*8)*1024 + k0 + tx] = (unsigned short)(lo >> 16);
    }
}

// ---------------- kernel 1: y[m] = sum_u relu(x[m,:]·W[:,u] + db[u]) * wv[u]
// bf16-split MFMA: x=xh+xl, W=Wh+Wl; acc += xh·Wh + xh·Wl + xl·Wh (fp32 acc).
// 128x128 tile, 4 waves (64x64 each), BK=64, XOR-swizzled LDS.
__global__ __launch_bounds__(256, 2) void cif_gemm_mfma(
    const float* __restrict__ x,
    const unsigned short* __restrict__ WhT,
    const unsigned short* __restrict__ WlT,
    const float* __restrict__ db,
    const float* __restrict__ wvv,
    float* __restrict__ y)
{
    __shared__ unsigned short Ah[128*64];
    __shared__ unsigned short Al[128*64];
    __shared__ unsigned short Bh[128*64];
    __shared__ unsigned short Bl[128*64];
    const int tid  = threadIdx.x;
    const int lane = tid & 63;
    const int wid  = tid >> 6;           // wave 0..3
    const int wr   = wid >> 1, wc = wid & 1;
    const int m0   = blockIdx.x * 128;
    const int li   = lane & 15, q = lane >> 4;

    float pp[4][4];                      // per-thread row partials [mt][r]
#pragma unroll
    for (int i = 0; i < 4; ++i)
#pragma unroll
        for (int j = 0; j < 4; ++j) pp[i][j] = 0.f;

    const int a_row = tid >> 4;          // 16 rows per round
    const int a_c4  = tid & 15;          // float4 slot in 64-k row
    const int b_row = tid >> 3;          // 32 rows per round
    const int b_ch  = tid & 7;           // 16B chunk in 64-k row

    for (int nb = 0; nb < 8; ++nb) {
        f32x4 acc[4][4];
#pragma unroll
        for (int i = 0; i < 4; ++i)
#pragma unroll
            for (int j = 0; j < 4; ++j) acc[i][j] = (f32x4){0.f,0.f,0.f,0.f};

        for (int k0 = 0; k0 < 1024; k0 += 64) {
            // ---- stage A: f32 load, truncation-split to bf16 hi/lo
#pragma unroll
            for (int r = 0; r < 8; ++r) {
                const int m = r*16 + a_row;
                const float4 v = *(const float4*)(x + (size_t)(m0+m)*1024 + k0 + a_c4*4);
                const unsigned u0 = __float_as_uint(v.x);
                const unsigned u1 = __float_as_uint(v.y);
                const unsigned u2 = __float_as_uint(v.z);
                const unsigned u3 = __float_as_uint(v.w);
                us4 h4, l4;
                h4[0]=(unsigned short)(u0>>16); h4[1]=(unsigned short)(u1>>16);
                h4[2]=(unsigned short)(u2>>16); h4[3]=(unsigned short)(u3>>16);
                l4[0]=(unsigned short)(__float_as_uint(v.x - __uint_as_float(u0 & 0xFFFF0000u))>>16);
                l4[1]=(unsigned short)(__float_as_uint(v.y - __uint_as_float(u1 & 0xFFFF0000u))>>16);
                l4[2]=(unsigned short)(__float_as_uint(v.z - __uint_as_float(u2 & 0xFFFF0000u))>>16);
                l4[3]=(unsigned short)(__float_as_uint(v.w - __uint_as_float(u3 & 0xFFFF0000u))>>16);
                const int addr = m*64 + ((a_c4*4) ^ ((m & 7) << 3));
                *(us4*)&Ah[addr] = h4;
                *(us4*)&Al[addr] = l4;
            }
            // ---- stage B: bf16 copy from W^T hi/lo
#pragma unroll
            for (int r = 0; r < 4; ++r) {
                const int n = r*32 + b_row;
                const size_t src = (size_t)(nb*128 + n)*1024 + k0 + b_ch*8;
                const int addr = n*64 + ((b_ch*8) ^ ((n & 7) << 3));
                *(us8*)&Bh[addr] = *(const us8*)(WhT + src);
                *(us8*)&Bl[addr] = *(const us8*)(WlT + src);
            }
            __syncthreads();
            // ---- MFMA
#pragma unroll
            for (int kb = 0; kb < 64; kb += 32) {
                bf16x8 ah[4], al[4], bh[4], bl[4];
                const int kk = kb + q*8;
#pragma unroll
                for (int mt = 0; mt < 4; ++mt) {
                    const int m = wr*64 + mt*16 + li;
                    const int addr = m*64 + (kk ^ ((m & 7) << 3));
                    ah[mt] = *(const bf16x8*)&Ah[addr];
                    al[mt] = *(const bf16x8*)&Al[addr];
                }
#pragma unroll
                for (int nt = 0; nt < 4; ++nt) {
                    const int n = wc*64 + nt*16 + li;
                    const int addr = n*64 + (kk ^ ((n & 7) << 3));
                    bh[nt] = *(const bf16x8*)&Bh[addr];
                    bl[nt] = *(const bf16x8*)&Bl[addr];
                }
#pragma unroll
                for (int mt = 0; mt < 4; ++mt)
#pragma unroll
                    for (int nt = 0; nt < 4; ++nt) {
                        acc[mt][nt] = __builtin_amdgcn_mfma_f32_16x16x32_bf16(ah[mt], bh[nt], acc[mt][nt], 0, 0, 0);
                        acc[mt][nt] = __builtin_amdgcn_mfma_f32_16x16x32_bf16(ah[mt], bl[nt], acc[mt][nt], 0, 0, 0);
                        acc[mt][nt] = __builtin_amdgcn_mfma_f32_16x16x32_bf16(al[mt], bh[nt], acc[mt][nt], 0, 0, 0);
                    }
            }
            __syncthreads();
        }
        // ---- epilogue for this N-block: bias + relu + dot(wv) into row partials
#pragma unroll
        for (int nt = 0; nt < 4; ++nt) {
            const int c = nb*128 + wc*64 + nt*16 + li;
            const float dbc = db[c], wvc = wvv[c];
#pragma unroll
            for (int mt = 0; mt < 4; ++mt)
#pragma unroll
                for (int r = 0; r < 4; ++r) {
                    float h = acc[mt][nt][r] + dbc;
                    h = fmaxf(h, 0.f);
                    pp[mt][r] = fmaf(h, wvc, pp[mt][r]);
                }
        }
    }
    // deterministic reduce: width-16 butterfly (cols within wave) ...
#pragma unroll
    for (int s = 1; s < 16; s <<= 1)
#pragma unroll
        for (int mt = 0; mt < 4; ++mt)
#pragma unroll
            for (int r = 0; r < 4; ++r)
                pp[mt][r] += __shfl_xor(pp[mt][r], s, 16);
    // ... then cross-wave (wc=0 + wc=1) combine via LDS. Each row's 1024 cols
    // are split across the two wc-waves; the R2 bug was racing y-writes here.
    __syncthreads();
    float* red = (float*)Ah;             // 256 floats, reuse staging LDS
    if (li == 0) {
#pragma unroll
        for (int mt = 0; mt < 4; ++mt)
#pragma unroll
            for (int r = 0; r < 4; ++r)
                red[wc*128 + wr*64 + mt*16 + q*4 + r] = pp[mt][r];
    }
    __syncthreads();
    if (tid < 128)
        y[m0 + tid] = red[tid] + red[128 + tid];
}

// ---------------- kernel 2: sigmoid, mask, per-batch sum (fp64), quantity, normalize
__global__ __launch_bounds__(256) void cif_wnorm(const float* __restrict__ y,
                                                 const unsigned char* __restrict__ mask,
                                                 const int* __restrict__ tlen,
                                                 const float* __restrict__ wb,
                                                 float* __restrict__ wn,
                                                 float* __restrict__ qty,
                                                 int* __restrict__ padc)
{
    const int b = blockIdx.x, tid = threadIdx.x;
    const double wbias = (double)wb[0];
    double lsum = 0.0; int lpad = 0;
    for (int t = tid; t < T_; t += 256) {
        const double z = (double)y[b*T_ + t] + wbias;
        double s = 1.0 / (1.0 + exp(-z));
        const unsigned char mk = mask[b*T_ + t];
        if (mk) s = 0.0; else ++lpad;
        wn[b*T_ + t] = (float)s;
        lsum += s;
    }
    __shared__ double sred[256];
    __shared__ int    ired[256];
    sred[tid] = lsum; ired[tid] = lpad;
    __syncthreads();
    for (int st = 128; st > 0; st >>= 1) {
        if (tid < st) { sred[tid] += sred[tid+st]; ired[tid] += ired[tid+st]; }
        __syncthreads();
    }
    __shared__ double sc;
    if (tid == 0) {
        qty[b]  = (float)sred[0];
        sc      = (double)tlen[b] / sred[0];
        padc[b] = ired[0];
    }
    __syncthreads();
    const double scale = sc;
    for (int t = tid; t < T_; t += 256)
        wn[b*T_ + t] = (float)((double)wn[b*T_ + t] * scale);
}

// ---------------- kernel 3: scalar integrate-and-fire scan (one lane per batch)
__global__ void cif_scan(float* __restrict__ wn,
                         const int* __restrict__ padc,
                         int* __restrict__ fire_t,
                         float* __restrict__ carry,
                         int* __restrict__ nf)
{
    const int b = threadIdx.x;
    if (b >= B_) return;
    float acc = 0.f; int k = 0;
    const int pc = padc[b];
    float4 cur = *(const float4*)(wn + b*T_);
    for (int t4 = 0; t4 < T_/4; ++t4) {
        float4 nxt = cur;
        if (t4 + 1 < T_/4) nxt = *(const float4*)(wn + b*T_ + (t4+1)*4);
#pragma unroll
        for (int j = 0; j < 4; ++j) {
            const int t = t4*4 + j;
            const float w = (&cur.x)[j];
            const float s = acc + w;
            if (s >= 1.0f) {
                const float rem = 1.0f - acc;
                const float cw  = w - rem;
                if (t <= pc && k < 256) {
                    fire_t[b*256 + k] = t;
                    carry [b*256 + k] = cw;
                    wn[b*T_ + t] = rem;
                    ++k;
                }
                acc = cw;
            } else {
                acc = s;
            }
        }
        cur = nxt;
    }
    nf[b] = k;
}

// ---------------- kernel 4: segmented weighted gather -> cif_out rows (+ zero fill)
__global__ __launch_bounds__(256) void cif_scatter(const float* __restrict__ x,
                                                   const float* __restrict__ wn,
                                                   const int* __restrict__ fire_t,
                                                   const float* __restrict__ carry,
                                                   const int* __restrict__ nf,
                                                   float* __restrict__ out)
{
    const int k = blockIdx.x, b = blockIdx.y;
    const int d = threadIdx.x * 4;
    float ax = 0.f, ay = 0.f, az = 0.f, aw = 0.f;
    if (k < nf[b]) {
        const int tk = fire_t[b*256 + k];
        const float* xb = x + (size_t)b * T_ * 1024;
        int ts = 0;
        if (k > 0) {
            const int   tp = fire_t[b*256 + k - 1];
            const float c  = carry [b*256 + k - 1];
            const float4 xv = *(const float4*)(xb + (size_t)tp*1024 + d);
            ax = c*xv.x; ay = c*xv.y; az = c*xv.z; aw = c*xv.w;
            ts = tp + 1;
        }
        for (int t = ts; t <= tk; ++t) {
            const float c = wn[b*T_ + t];
            const float4 xv = *(const float4*)(xb + (size_t)t*1024 + d);
            ax = fmaf(c, xv.x, ax); ay = fmaf(c, xv.y, ay);
            az = fmaf(c, xv.z, az); aw = fmaf(c, xv.w, aw);
        }
    }
    float4 r; r.x = ax; r.y = ay; r.z = az; r.w = aw;
    *(float4*)(out + ((size_t)b*T_ + k)*1024 + d) = r;
}

// ---------------- kernel 5: cif_out_padding_mask (written as float 0/1)
__global__ void cif_mask(const int* __restrict__ nf, float* __restrict__ mout)
{
    const int i = blockIdx.x * 256 + threadIdx.x;
    if (i >= B_*T_) return;
    const int b = i / T_, t = i - b*T_;
    mout[i] = (t < nf[b]) ? 1.0f : 0.0f;
}

extern "C" void kernel_launch(void* const* d_in, const int* in_sizes, int n_in,
                              void* d_out, int out_size, void* d_ws, size_t ws_size,
                              hipStream_t stream)
{
    const float*         x    = (const float*)d_in[0];
    const unsigned char* mask = (const unsigned char*)d_in[1];
    const int*           tlen = (const int*)d_in[2];
    const float*         dW   = (const float*)d_in[3];
    const float*         db   = (const float*)d_in[4];
    const float*         wv   = (const float*)d_in[5];
    const float*         wb   = (const float*)d_in[6];

    float* out  = (float*)d_out;                 // cif_out [B,T,D]
    float* qty  = out + (size_t)B_*T_*D_;        // quantity_out [B]
    float* mout = qty + B_;                      // padding mask [B,T]

    float* ws     = (float*)d_ws;
    float* y      = ws;                                 // 64000
    float* wn     = ws + M_;                            // 64000
    float* carry  = ws + 2*M_;                          // 32*256
    int*   fire_t = (int*)(ws + 2*M_ + B_*256);         // 32*256
    int*   nf     = (int*)(ws + 2*M_ + 2*B_*256);       // 32
    int*   padc   = nf + B_;                            // 32
    // bf16 W^T hi/lo, 2 MB each, 256B-aligned region after the scalars
    size_t off = 2*(size_t)M_ + 2*B_*256 + 64;
    off = (off + 63) & ~(size_t)63;
    unsigned short* WhT = (unsigned short*)(ws + off);
    unsigned short* WlT = WhT + (size_t)U_*D_;

    wt_conv      <<<dim3(32, 32), 256, 0, stream>>>(dW, WhT, WlT);
    cif_gemm_mfma<<<M_/128,       256, 0, stream>>>(x, WhT, WlT, db, wv, y);
    cif_wnorm    <<<B_,           256, 0, stream>>>(y, mask, tlen, wb, wn, qty, padc);
    cif_scan     <<<1,             64, 0, stream>>>(wn, padc, fire_t, carry, nf);
    cif_scatter  <<<dim3(T_, B_), 256, 0, stream>>>(x, wn, fire_t, carry, nf, out);
    cif_mask     <<<(B_*T_ + 255)/256, 256, 0, stream>>>(nf, mout);
}

// Round 4
// 788.389 us; speedup vs baseline: 2.7069x; 1.4662x over previous
//
#include <hip/hip_runtime.h>
#include <cmath>

#define B_ 32
#define T_ 2000
#define D_ 1024
#define U_ 1024
#define M_ (B_*T_)

typedef float  f32x4  __attribute__((ext_vector_type(4)));
typedef short  bf16x8 __attribute__((ext_vector_type(8)));
typedef unsigned short us4 __attribute__((ext_vector_type(4)));
typedef unsigned short us8 __attribute__((ext_vector_type(8)));

// ---------------- kernel 0a: W [k][n] f32 -> W^T hi/lo bf16 [n][k]
__global__ __launch_bounds__(256) void wt_conv(const float* __restrict__ W,
                                               unsigned short* __restrict__ WhT,
                                               unsigned short* __restrict__ WlT)
{
    __shared__ float tl[32][33];
    const int tx = threadIdx.x & 31, ty = threadIdx.x >> 5;
    const int n0 = blockIdx.x * 32, k0 = blockIdx.y * 32;
#pragma unroll
    for (int i = 0; i < 4; ++i)
        tl[ty + i*8][tx] = W[(size_t)(k0 + ty + i*8)*1024 + n0 + tx];
    __syncthreads();
#pragma unroll
    for (int i = 0; i < 4; ++i) {
        const float f = tl[tx][ty + i*8];
        const unsigned u = __float_as_uint(f);
        const float hif = __uint_as_float(u & 0xFFFF0000u);
        const unsigned lo = __float_as_uint(f - hif);
        WhT[(size_t)(n0 + ty + i*8)*1024 + k0 + tx] = (unsigned short)(u >> 16);
        WlT[(size_t)(n0 + ty + i*8)*1024 + k0 + tx] = (unsigned short)(lo >> 16);
    }
}

// ---------------- kernel 0b: x f32 -> Xh/Xl bf16 (truncation split), grid-stride
__global__ __launch_bounds__(512) void xsplit(const float* __restrict__ x,
                                              unsigned short* __restrict__ Xh,
                                              unsigned short* __restrict__ Xl)
{
    const size_t n4 = (size_t)M_ * 1024 / 4;
    for (size_t i = (size_t)blockIdx.x * 512 + threadIdx.x; i < n4;
         i += (size_t)gridDim.x * 512) {
        const float4 v = ((const float4*)x)[i];
        const unsigned u0 = __float_as_uint(v.x);
        const unsigned u1 = __float_as_uint(v.y);
        const unsigned u2 = __float_as_uint(v.z);
        const unsigned u3 = __float_as_uint(v.w);
        us4 h, l;
        h[0]=(unsigned short)(u0>>16); h[1]=(unsigned short)(u1>>16);
        h[2]=(unsigned short)(u2>>16); h[3]=(unsigned short)(u3>>16);
        l[0]=(unsigned short)(__float_as_uint(v.x - __uint_as_float(u0 & 0xFFFF0000u))>>16);
        l[1]=(unsigned short)(__float_as_uint(v.y - __uint_as_float(u1 & 0xFFFF0000u))>>16);
        l[2]=(unsigned short)(__float_as_uint(v.z - __uint_as_float(u2 & 0xFFFF0000u))>>16);
        l[3]=(unsigned short)(__float_as_uint(v.w - __uint_as_float(u3 & 0xFFFF0000u))>>16);
        ((us4*)Xh)[i] = h;
        ((us4*)Xl)[i] = l;
    }
}

// ---------------- kernel 1: pipelined pre-split bf16 MFMA GEMM (primary path)
// y[m] = sum_u relu(x[m,:]·W[:,u] + db[u]) * wv[u]; acc += xh·Wh + xh·Wl + xl·Wh.
// 128x128 tile, 4 waves (64x64), BK=64, single LDS buffer, reg-staged pipeline.
__global__ __launch_bounds__(256, 2) void cif_gemm_ps(
    const unsigned short* __restrict__ Xh,
    const unsigned short* __restrict__ Xl,
    const unsigned short* __restrict__ WhT,
    const unsigned short* __restrict__ WlT,
    const float* __restrict__ db,
    const float* __restrict__ wvv,
    float* __restrict__ y)
{
    __shared__ unsigned short Ah[128*64];
    __shared__ unsigned short Al[128*64];
    __shared__ unsigned short Bh[128*64];
    __shared__ unsigned short Bl[128*64];
    const int tid  = threadIdx.x;
    const int lane = tid & 63;
    const int wid  = tid >> 6;
    const int wr   = wid >> 1, wc = wid & 1;
    const int m0   = blockIdx.x * 128;
    const int li   = lane & 15, q = lane >> 4;
    const int s_row = tid >> 3;     // 32 rows per round
    const int s_ch  = tid & 7;      // us8 chunk in 64-k row

    float pp[4][4];
#pragma unroll
    for (int i = 0; i < 4; ++i)
#pragma unroll
        for (int j = 0; j < 4; ++j) pp[i][j] = 0.f;

    us8 ra[4], rla[4], rb[4], rlb[4];
    f32x4 acc[4][4];

    auto LOADSTAGE = [&](int nb, int kt) {
        const size_t koff = (size_t)kt*64 + s_ch*8;
#pragma unroll
        for (int r = 0; r < 4; ++r) {
            const int row = r*32 + s_row;
            ra [r] = *(const us8*)(Xh  + (size_t)(m0+row)*1024 + koff);
            rla[r] = *(const us8*)(Xl  + (size_t)(m0+row)*1024 + koff);
            rb [r] = *(const us8*)(WhT + (size_t)(nb*128+row)*1024 + koff);
            rlb[r] = *(const us8*)(WlT + (size_t)(nb*128+row)*1024 + koff);
        }
    };
    auto WRITESTAGE = [&]() {
#pragma unroll
        for (int r = 0; r < 4; ++r) {
            const int row  = r*32 + s_row;
            const int addr = row*64 + ((s_ch*8) ^ ((row & 7) << 3));
            *(us8*)&Ah[addr] = ra[r];
            *(us8*)&Al[addr] = rla[r];
            *(us8*)&Bh[addr] = rb[r];
            *(us8*)&Bl[addr] = rlb[r];
        }
    };

    LOADSTAGE(0, 0);
    for (int it = 0; it < 128; ++it) {
        const int nb = it >> 4, kt = it & 15;
        if (kt == 0) {
#pragma unroll
            for (int i = 0; i < 4; ++i)
#pragma unroll
                for (int j = 0; j < 4; ++j) acc[i][j] = (f32x4){0.f,0.f,0.f,0.f};
        }
        if (it) __syncthreads();        // all waves done reading previous tile
        WRITESTAGE();
        __syncthreads();                // tile visible
        if (it + 1 < 128) LOADSTAGE((it+1) >> 4, (it+1) & 15);  // in flight under MFMA
#pragma unroll
        for (int kb = 0; kb < 2; ++kb) {
            const int kk = kb*32 + q*8;
            bf16x8 ah[4], al[4], bh[4], bl[4];
#pragma unroll
            for (int mt = 0; mt < 4; ++mt) {
                const int m = wr*64 + mt*16 + li;
                const int addr = m*64 + (kk ^ ((m & 7) << 3));
                ah[mt] = *(const bf16x8*)&Ah[addr];
                al[mt] = *(const bf16x8*)&Al[addr];
            }
#pragma unroll
            for (int nt = 0; nt < 4; ++nt) {
                const int n = wc*64 + nt*16 + li;
                const int addr = n*64 + (kk ^ ((n & 7) << 3));
                bh[nt] = *(const bf16x8*)&Bh[addr];
                bl[nt] = *(const bf16x8*)&Bl[addr];
            }
#pragma unroll
            for (int mt = 0; mt < 4; ++mt)
#pragma unroll
                for (int nt = 0; nt < 4; ++nt) {
                    acc[mt][nt] = __builtin_amdgcn_mfma_f32_16x16x32_bf16(ah[mt], bh[nt], acc[mt][nt], 0, 0, 0);
                    acc[mt][nt] = __builtin_amdgcn_mfma_f32_16x16x32_bf16(ah[mt], bl[nt], acc[mt][nt], 0, 0, 0);
                    acc[mt][nt] = __builtin_amdgcn_mfma_f32_16x16x32_bf16(al[mt], bh[nt], acc[mt][nt], 0, 0, 0);
                }
        }
        if (kt == 15) {
#pragma unroll
            for (int nt = 0; nt < 4; ++nt) {
                const int c = nb*128 + wc*64 + nt*16 + li;
                const float dbc = db[c], wvc = wvv[c];
#pragma unroll
                for (int mt = 0; mt < 4; ++mt)
#pragma unroll
                    for (int r = 0; r < 4; ++r) {
                        float h = acc[mt][nt][r] + dbc;
                        h = fmaxf(h, 0.f);
                        pp[mt][r] = fmaf(h, wvc, pp[mt][r]);
                    }
            }
        }
    }
    // width-16 butterfly, then cross-wave (wc) combine via LDS
#pragma unroll
    for (int s = 1; s < 16; s <<= 1)
#pragma unroll
        for (int mt = 0; mt < 4; ++mt)
#pragma unroll
            for (int r = 0; r < 4; ++r)
                pp[mt][r] += __shfl_xor(pp[mt][r], s, 16);
    __syncthreads();
    float* red = (float*)Ah;
    if (li == 0) {
#pragma unroll
        for (int mt = 0; mt < 4; ++mt)
#pragma unroll
            for (int r = 0; r < 4; ++r)
                red[wc*128 + wr*64 + mt*16 + q*4 + r] = pp[mt][r];
    }
    __syncthreads();
    if (tid < 128)
        y[m0 + tid] = red[tid] + red[128 + tid];
}

// ---------------- kernel 1-fb: R3 in-kernel-split GEMM (fallback if ws too small)
__global__ __launch_bounds__(256, 2) void cif_gemm_fb(
    const float* __restrict__ x,
    const unsigned short* __restrict__ WhT,
    const unsigned short* __restrict__ WlT,
    const float* __restrict__ db,
    const float* __restrict__ wvv,
    float* __restrict__ y)
{
    __shared__ unsigned short Ah[128*64];
    __shared__ unsigned short Al[128*64];
    __shared__ unsigned short Bh[128*64];
    __shared__ unsigned short Bl[128*64];
    const int tid  = threadIdx.x;
    const int lane = tid & 63;
    const int wid  = tid >> 6;
    const int wr   = wid >> 1, wc = wid & 1;
    const int m0   = blockIdx.x * 128;
    const int li   = lane & 15, q = lane >> 4;

    float pp[4][4];
#pragma unroll
    for (int i = 0; i < 4; ++i)
#pragma unroll
        for (int j = 0; j < 4; ++j) pp[i][j] = 0.f;

    const int a_row = tid >> 4;
    const int a_c4  = tid & 15;
    const int b_row = tid >> 3;
    const int b_ch  = tid & 7;

    for (int nb = 0; nb < 8; ++nb) {
        f32x4 acc[4][4];
#pragma unroll
        for (int i = 0; i < 4; ++i)
#pragma unroll
            for (int j = 0; j < 4; ++j) acc[i][j] = (f32x4){0.f,0.f,0.f,0.f};

        for (int k0 = 0; k0 < 1024; k0 += 64) {
#pragma unroll
            for (int r = 0; r < 8; ++r) {
                const int m = r*16 + a_row;
                const float4 v = *(const float4*)(x + (size_t)(m0+m)*1024 + k0 + a_c4*4);
                const unsigned u0 = __float_as_uint(v.x);
                const unsigned u1 = __float_as_uint(v.y);
                const unsigned u2 = __float_as_uint(v.z);
                const unsigned u3 = __float_as_uint(v.w);
                us4 h4, l4;
                h4[0]=(unsigned short)(u0>>16); h4[1]=(unsigned short)(u1>>16);
                h4[2]=(unsigned short)(u2>>16); h4[3]=(unsigned short)(u3>>16);
                l4[0]=(unsigned short)(__float_as_uint(v.x - __uint_as_float(u0 & 0xFFFF0000u))>>16);
                l4[1]=(unsigned short)(__float_as_uint(v.y - __uint_as_float(u1 & 0xFFFF0000u))>>16);
                l4[2]=(unsigned short)(__float_as_uint(v.z - __uint_as_float(u2 & 0xFFFF0000u))>>16);
                l4[3]=(unsigned short)(__float_as_uint(v.w - __uint_as_float(u3 & 0xFFFF0000u))>>16);
                const int addr = m*64 + ((a_c4*4) ^ ((m & 7) << 3));
                *(us4*)&Ah[addr] = h4;
                *(us4*)&Al[addr] = l4;
            }
#pragma unroll
            for (int r = 0; r < 4; ++r) {
                const int n = r*32 + b_row;
                const size_t src = (size_t)(nb*128 + n)*1024 + k0 + b_ch*8;
                const int addr = n*64 + ((b_ch*8) ^ ((n & 7) << 3));
                *(us8*)&Bh[addr] = *(const us8*)(WhT + src);
                *(us8*)&Bl[addr] = *(const us8*)(WlT + src);
            }
            __syncthreads();
#pragma unroll
            for (int kb = 0; kb < 64; kb += 32) {
                bf16x8 ah[4], al[4], bh[4], bl[4];
                const int kk = kb + q*8;
#pragma unroll
                for (int mt = 0; mt < 4; ++mt) {
                    const int m = wr*64 + mt*16 + li;
                    const int addr = m*64 + (kk ^ ((m & 7) << 3));
                    ah[mt] = *(const bf16x8*)&Ah[addr];
                    al[mt] = *(const bf16x8*)&Al[addr];
                }
#pragma unroll
                for (int nt = 0; nt < 4; ++nt) {
                    const int n = wc*64 + nt*16 + li;
                    const int addr = n*64 + (kk ^ ((n & 7) << 3));
                    bh[nt] = *(const bf16x8*)&Bh[addr];
                    bl[nt] = *(const bf16x8*)&Bl[addr];
                }
#pragma unroll
                for (int mt = 0; mt < 4; ++mt)
#pragma unroll
                    for (int nt = 0; nt < 4; ++nt) {
                        acc[mt][nt] = __builtin_amdgcn_mfma_f32_16x16x32_bf16(ah[mt], bh[nt], acc[mt][nt], 0, 0, 0);
                        acc[mt][nt] = __builtin_amdgcn_mfma_f32_16x16x32_bf16(ah[mt], bl[nt], acc[mt][nt], 0, 0, 0);
                        acc[mt][nt] = __builtin_amdgcn_mfma_f32_16x16x32_bf16(al[mt], bh[nt], acc[mt][nt], 0, 0, 0);
                    }
            }
            __syncthreads();
        }
#pragma unroll
        for (int nt = 0; nt < 4; ++nt) {
            const int c = nb*128 + wc*64 + nt*16 + li;
            const float dbc = db[c], wvc = wvv[c];
#pragma unroll
            for (int mt = 0; mt < 4; ++mt)
#pragma unroll
                for (int r = 0; r < 4; ++r) {
                    float h = acc[mt][nt][r] + dbc;
                    h = fmaxf(h, 0.f);
                    pp[mt][r] = fmaf(h, wvc, pp[mt][r]);
                }
        }
    }
#pragma unroll
    for (int s = 1; s < 16; s <<= 1)
#pragma unroll
        for (int mt = 0; mt < 4; ++mt)
#pragma unroll
            for (int r = 0; r < 4; ++r)
                pp[mt][r] += __shfl_xor(pp[mt][r], s, 16);
    __syncthreads();
    float* red = (float*)Ah;
    if (li == 0) {
#pragma unroll
        for (int mt = 0; mt < 4; ++mt)
#pragma unroll
            for (int r = 0; r < 4; ++r)
                red[wc*128 + wr*64 + mt*16 + q*4 + r] = pp[mt][r];
    }
    __syncthreads();
    if (tid < 128)
        y[m0 + tid] = red[tid] + red[128 + tid];
}

// ---------------- kernel 2: sigmoid, mask, per-batch sum (fp64), quantity, normalize
__global__ __launch_bounds__(256) void cif_wnorm(const float* __restrict__ y,
                                                 const unsigned char* __restrict__ mask,
                                                 const int* __restrict__ tlen,
                                                 const float* __restrict__ wb,
                                                 float* __restrict__ wn,
                                                 float* __restrict__ qty,
                                                 int* __restrict__ padc)
{
    const int b = blockIdx.x, tid = threadIdx.x;
    const double wbias = (double)wb[0];
    double lsum = 0.0; int lpad = 0;
    for (int t = tid; t < T_; t += 256) {
        const double z = (double)y[b*T_ + t] + wbias;
        double s = 1.0 / (1.0 + exp(-z));
        const unsigned char mk = mask[b*T_ + t];
        if (mk) s = 0.0; else ++lpad;
        wn[b*T_ + t] = (float)s;
        lsum += s;
    }
    __shared__ double sred[256];
    __shared__ int    ired[256];
    sred[tid] = lsum; ired[tid] = lpad;
    __syncthreads();
    for (int st = 128; st > 0; st >>= 1) {
        if (tid < st) { sred[tid] += sred[tid+st]; ired[tid] += ired[tid+st]; }
        __syncthreads();
    }
    __shared__ double sc;
    if (tid == 0) {
        qty[b]  = (float)sred[0];
        sc      = (double)tlen[b] / sred[0];
        padc[b] = ired[0];
    }
    __syncthreads();
    const double scale = sc;
    for (int t = tid; t < T_; t += 256)
        wn[b*T_ + t] = (float)((double)wn[b*T_ + t] * scale);
}

// ---------------- kernel 3: scalar integrate-and-fire scan (one lane per batch)
__global__ void cif_scan(float* __restrict__ wn,
                         const int* __restrict__ padc,
                         int* __restrict__ fire_t,
                         float* __restrict__ carry,
                         int* __restrict__ nf)
{
    const int b = threadIdx.x;
    if (b >= B_) return;
    float acc = 0.f; int k = 0;
    const int pc = padc[b];
    float4 cur = *(const float4*)(wn + b*T_);
    for (int t4 = 0; t4 < T_/4; ++t4) {
        float4 nxt = cur;
        if (t4 + 1 < T_/4) nxt = *(const float4*)(wn + b*T_ + (t4+1)*4);
#pragma unroll
        for (int j = 0; j < 4; ++j) {
            const int t = t4*4 + j;
            const float w = (&cur.x)[j];
            const float s = acc + w;
            if (s >= 1.0f) {
                const float rem = 1.0f - acc;
                const float cw  = w - rem;
                if (t <= pc && k < 256) {
                    fire_t[b*256 + k] = t;
                    carry [b*256 + k] = cw;
                    wn[b*T_ + t] = rem;
                    ++k;
                }
                acc = cw;
            } else {
                acc = s;
            }
        }
        cur = nxt;
    }
    nf[b] = k;
}

// ---------------- kernel 4: segmented weighted gather -> cif_out rows (+ zero fill)
__global__ __launch_bounds__(256) void cif_scatter(const float* __restrict__ x,
                                                   const float* __restrict__ wn,
                                                   const int* __restrict__ fire_t,
                                                   const float* __restrict__ carry,
                                                   const int* __restrict__ nf,
                                                   float* __restrict__ out)
{
    const int k = blockIdx.x, b = blockIdx.y;
    const int d = threadIdx.x * 4;
    float ax = 0.f, ay = 0.f, az = 0.f, aw = 0.f;
    if (k < nf[b]) {
        const int tk = fire_t[b*256 + k];
        const float* xb = x + (size_t)b * T_ * 1024;
        int ts = 0;
        if (k > 0) {
            const int   tp = fire_t[b*256 + k - 1];
            const float c  = carry [b*256 + k - 1];
            const float4 xv = *(const float4*)(xb + (size_t)tp*1024 + d);
            ax = c*xv.x; ay = c*xv.y; az = c*xv.z; aw = c*xv.w;
            ts = tp + 1;
        }
        for (int t = ts; t <= tk; ++t) {
            const float c = wn[b*T_ + t];
            const float4 xv = *(const float4*)(xb + (size_t)t*1024 + d);
            ax = fmaf(c, xv.x, ax); ay = fmaf(c, xv.y, ay);
            az = fmaf(c, xv.z, az); aw = fmaf(c, xv.w, aw);
        }
    }
    float4 r; r.x = ax; r.y = ay; r.z = az; r.w = aw;
    *(float4*)(out + ((size_t)b*T_ + k)*1024 + d) = r;
}

// ---------------- kernel 5: cif_out_padding_mask (written as float 0/1)
__global__ void cif_mask(const int* __restrict__ nf, float* __restrict__ mout)
{
    const int i = blockIdx.x * 256 + threadIdx.x;
    if (i >= B_*T_) return;
    const int b = i / T_, t = i - b*T_;
    mout[i] = (t < nf[b]) ? 1.0f : 0.0f;
}

extern "C" void kernel_launch(void* const* d_in, const int* in_sizes, int n_in,
                              void* d_out, int out_size, void* d_ws, size_t ws_size,
                              hipStream_t stream)
{
    const float*         x    = (const float*)d_in[0];
    const unsigned char* mask = (const unsigned char*)d_in[1];
    const int*           tlen = (const int*)d_in[2];
    const float*         dW   = (const float*)d_in[3];
    const float*         db   = (const float*)d_in[4];
    const float*         wv   = (const float*)d_in[5];
    const float*         wb   = (const float*)d_in[6];

    float* out  = (float*)d_out;                 // cif_out [B,T,D]
    float* qty  = out + (size_t)B_*T_*D_;        // quantity_out [B]
    float* mout = qty + B_;                      // padding mask [B,T]

    float* ws     = (float*)d_ws;
    float* y      = ws;                                 // 64000
    float* wn     = ws + M_;                            // 64000
    float* carry  = ws + 2*M_;                          // 32*256
    int*   fire_t = (int*)(ws + 2*M_ + B_*256);         // 32*256
    int*   nf     = (int*)(ws + 2*M_ + 2*B_*256);       // 32
    int*   padc   = nf + B_;                            // 32
    size_t off = 2*(size_t)M_ + 2*B_*256 + 64;
    off = (off + 63) & ~(size_t)63;
    unsigned short* WhT = (unsigned short*)(ws + off);
    unsigned short* WlT = WhT + (size_t)U_*D_;
    unsigned short* Xh  = WlT + (size_t)U_*D_;
    unsigned short* Xl  = Xh  + (size_t)M_*D_;
    const size_t need = off*sizeof(float)
                      + 2*(size_t)U_*D_*sizeof(unsigned short)
                      + 2*(size_t)M_*D_*sizeof(unsigned short);

    wt_conv<<<dim3(32, 32), 256, 0, stream>>>(dW, WhT, WlT);
    if (ws_size >= need) {
        xsplit     <<<2048, 512, 0, stream>>>(x, Xh, Xl);
        cif_gemm_ps<<<M_/128, 256, 0, stream>>>(Xh, Xl, WhT, WlT, db, wv, y);
    } else {
        cif_gemm_fb<<<M_/128, 256, 0, stream>>>(x, WhT, WlT, db, wv, y);
    }
    cif_wnorm  <<<B_,           256, 0, stream>>>(y, mask, tlen, wb, wn, qty, padc);
    cif_scan   <<<1,             64, 0, stream>>>(wn, padc, fire_t, carry, nf);
    cif_scatter<<<dim3(T_, B_), 256, 0, stream>>>(x, wn, fire_t, carry, nf, out);
    cif_mask   <<<(B_*T_ + 255)/256, 256, 0, stream>>>(nf, mout);
}